// Round 1
// baseline (6551.628 us; speedup 1.0000x reference)
//
#include <hip/hip_runtime.h>
#include <hip/hip_bf16.h>
#include <cstdio>

#define BATCH 8
#define CIN 256
#define L0 16384
#define NRES 32
#define NSKIP 512
#define NL 50
#define FINAL_LEN 11269
#define FL_PAD 11272

__device__ __forceinline__ float bfr(unsigned short u) {
    union { unsigned int i; float f; } v; v.i = ((unsigned int)u) << 16; return v.f;
}

// ---------------------------------------------------------------- bias sum
__global__ void k_bias_sum(const float* __restrict__ b_skip, float* __restrict__ bsum) {
    int o = threadIdx.x;
    if (o < NSKIP) {
        float s = 0.f;
        for (int i = 0; i < NL; ++i) s += b_skip[i * NSKIP + o];
        bsum[o] = s;
    }
}

// ---------------------------------------------------------------- input 1x1 conv 256->32
__global__ __launch_bounds__(256) void k_conv_in(
    const float* __restrict__ x, const float* __restrict__ w,
    const float* __restrict__ bias, float* __restrict__ out) {
    const int b = blockIdx.y;
    const int t = blockIdx.x * 256 + threadIdx.x;
    float acc[NRES];
#pragma unroll
    for (int o = 0; o < NRES; ++o) acc[o] = bias[o];
    const float* xp = x + (size_t)b * CIN * L0 + t;
    for (int c = 0; c < CIN; ++c) {
        float xv = xp[(size_t)c * L0];
#pragma unroll
        for (int o = 0; o < NRES; ++o) acc[o] = fmaf(w[o * CIN + c], xv, acc[o]);
    }
    float* op = out + (size_t)b * NRES * L0 + t;
#pragma unroll
    for (int o = 0; o < NRES; ++o) op[(size_t)o * L0] = acc[o];
}

// ---------------------------------------------------------------- one WaveNet layer
__global__ __launch_bounds__(256) void k_layer(
    const float* __restrict__ src, float* __restrict__ dst,
    __hip_bfloat16* __restrict__ gout,
    const float* __restrict__ wsig, const float* __restrict__ bsig,
    const float* __restrict__ wtan, const float* __restrict__ btan,
    const float* __restrict__ wres, const float* __restrict__ bres,
    int d, int out_len) {
    const int b = blockIdx.y;
    const int t = blockIdx.x * 256 + threadIdx.x;
    if (t >= out_len) return;
    const float* sp = src + (size_t)b * NRES * L0;

    float ps[NRES], pt[NRES];
#pragma unroll
    for (int o = 0; o < NRES; ++o) { ps[o] = bsig[o]; pt[o] = btan[o]; }

    for (int c = 0; c < NRES; ++c) {
        float xa = sp[(size_t)c * L0 + t];
        float xb = sp[(size_t)c * L0 + t + d];
#pragma unroll
        for (int o = 0; o < NRES; ++o) {
            ps[o] = fmaf(wsig[o * 64 + c * 2], xa, ps[o]);
            ps[o] = fmaf(wsig[o * 64 + c * 2 + 1], xb, ps[o]);
            pt[o] = fmaf(wtan[o * 64 + c * 2], xa, pt[o]);
            pt[o] = fmaf(wtan[o * 64 + c * 2 + 1], xb, pt[o]);
        }
    }

    float g[NRES];
#pragma unroll
    for (int o = 0; o < NRES; ++o) {
        float s  = 1.f / (1.f + __expf(-ps[o]));
        float e2 = __expf(2.f * pt[o]);
        float th = 1.f - 2.f / (e2 + 1.f);
        g[o] = s * th;
    }

    float* dp = dst + (size_t)b * NRES * L0;
#pragma unroll
    for (int o = 0; o < NRES; ++o) {
        float r = bres[o];
#pragma unroll
        for (int c = 0; c < NRES; ++c) r = fmaf(wres[o * 32 + c], g[c], r);
        dp[(size_t)o * L0 + t] = r + sp[(size_t)o * L0 + t + d];
    }

    const int t0 = out_len - FINAL_LEN;
    if (t >= t0) {
        const int tg = t - t0;
#pragma unroll
        for (int o = 0; o < NRES; ++o)
            gout[(size_t)(b * NRES + o) * FL_PAD + tg] = __float2bfloat16(g[o]);
    }
}

// ---------------------------------------------------------------- tiled fp32 GEMM
// MODE 0: A = w_skip [50][512][32], B = gates [50][8][32][FL_PAD], KTOT=1600
// MODE 1: A = W[M][KTOT],           B = buf   [8][KTOT][FL_PAD]
template <int KTOT, int MODE, bool DOELU, bool OBF16>
__global__ __launch_bounds__(256) void k_gemm(
    const float* __restrict__ A, const float* __restrict__ bias,
    const __hip_bfloat16* __restrict__ Bmat,
    float* __restrict__ outF, __hip_bfloat16* __restrict__ outH, int M) {
    const int tid = threadIdx.x;
    const int tm = tid >> 4, tn = tid & 15;
    const int l0 = blockIdx.x * 128;
    const int m0 = blockIdx.y * 128;
    const int bb = blockIdx.z;

    __shared__ float As[32][128];
    __shared__ float Bs[32][128];

    float acc[8][8];
#pragma unroll
    for (int i = 0; i < 8; ++i)
#pragma unroll
        for (int j = 0; j < 8; ++j) acc[i][j] = 0.f;

    for (int kb = 0; kb < KTOT; kb += 32) {
        // stage A: 128 rows x 32 k
#pragma unroll
        for (int r = 0; r < 4; ++r) {
            int f = tid * 16 + r * 4;
            int o = f >> 5, c = f & 31;
            const float* ap = (MODE == 0)
                ? A + (size_t)(kb >> 5) * (NSKIP * NRES) + (size_t)(m0 + o) * NRES + c
                : A + (size_t)(m0 + o) * KTOT + kb + c;
            float4 v = *(const float4*)ap;
            As[c + 0][o] = v.x; As[c + 1][o] = v.y; As[c + 2][o] = v.z; As[c + 3][o] = v.w;
        }
        // stage B: 32 k x 128 cols (bf16 -> fp32)
#pragma unroll
        for (int r = 0; r < 4; ++r) {
            int f = tid * 16 + r * 4;
            int c = f >> 7, n = f & 127;
            size_t row = (MODE == 0)
                ? ((size_t)(((kb >> 5) * BATCH + bb) * NRES) + c)
                : ((size_t)bb * KTOT + kb + c);
            int col = l0 + n;
            float v0, v1, v2, v3;
            if (col + 3 < FINAL_LEN) {
                short4 sv = *(const short4*)(Bmat + row * FL_PAD + col);
                v0 = bfr((unsigned short)sv.x); v1 = bfr((unsigned short)sv.y);
                v2 = bfr((unsigned short)sv.z); v3 = bfr((unsigned short)sv.w);
            } else {
                const unsigned short* up = (const unsigned short*)(Bmat + row * FL_PAD);
                v0 = (col + 0 < FINAL_LEN) ? bfr(up[col + 0]) : 0.f;
                v1 = (col + 1 < FINAL_LEN) ? bfr(up[col + 1]) : 0.f;
                v2 = (col + 2 < FINAL_LEN) ? bfr(up[col + 2]) : 0.f;
                v3 = (col + 3 < FINAL_LEN) ? bfr(up[col + 3]) : 0.f;
            }
            Bs[c][n + 0] = v0; Bs[c][n + 1] = v1; Bs[c][n + 2] = v2; Bs[c][n + 3] = v3;
        }
        __syncthreads();

#pragma unroll
        for (int k = 0; k < 32; ++k) {
            float ar[8], br[8];
            float4 a0 = *(const float4*)&As[k][tm * 4];
            float4 a1 = *(const float4*)&As[k][64 + tm * 4];
            float4 b0 = *(const float4*)&Bs[k][tn * 4];
            float4 b1 = *(const float4*)&Bs[k][64 + tn * 4];
            ar[0] = a0.x; ar[1] = a0.y; ar[2] = a0.z; ar[3] = a0.w;
            ar[4] = a1.x; ar[5] = a1.y; ar[6] = a1.z; ar[7] = a1.w;
            br[0] = b0.x; br[1] = b0.y; br[2] = b0.z; br[3] = b0.w;
            br[4] = b1.x; br[5] = b1.y; br[6] = b1.z; br[7] = b1.w;
#pragma unroll
            for (int i = 0; i < 8; ++i)
#pragma unroll
                for (int j = 0; j < 8; ++j) acc[i][j] = fmaf(ar[i], br[j], acc[i][j]);
        }
        __syncthreads();
    }

    // epilogue
#pragma unroll
    for (int ih = 0; ih < 2; ++ih)
#pragma unroll
        for (int i = 0; i < 4; ++i) {
            int row = m0 + ih * 64 + tm * 4 + i;
            float bv = bias[row];
#pragma unroll
            for (int jh = 0; jh < 2; ++jh)
#pragma unroll
                for (int j = 0; j < 4; ++j) {
                    int col = l0 + jh * 64 + tn * 4 + j;
                    if (col < FINAL_LEN) {
                        float v = acc[ih * 4 + i][jh * 4 + j] + bv;
                        if (DOELU) v = (v > 0.f) ? v : (__expf(v) - 1.f);
                        if (OBF16)
                            outH[(size_t)(bb * M + row) * FL_PAD + col] = __float2bfloat16(v);
                        else
                            outF[((size_t)bb * M + row) * FINAL_LEN + col] = v;
                    }
                }
        }
}

// ---------------------------------------------------------------- host
extern "C" void kernel_launch(void* const* d_in, const int* in_sizes, int n_in,
                              void* d_out, int out_size, void* d_ws, size_t ws_size,
                              hipStream_t stream) {
    const float* x      = (const float*)d_in[0];
    const float* w_in   = (const float*)d_in[1];
    const float* b_in   = (const float*)d_in[2];
    const float* w_sig  = (const float*)d_in[3];
    const float* b_sig  = (const float*)d_in[4];
    const float* w_tanh = (const float*)d_in[5];
    const float* b_tanh = (const float*)d_in[6];
    const float* w_skip = (const float*)d_in[7];
    const float* b_skip = (const float*)d_in[8];
    const float* w_res  = (const float*)d_in[9];
    const float* b_res  = (const float*)d_in[10];
    const float* w_p1   = (const float*)d_in[11];
    const float* b_p1   = (const float*)d_in[12];
    const float* w_p2   = (const float*)d_in[13];
    const float* b_p2   = (const float*)d_in[14];
    float* out = (float*)d_out;

    constexpr size_t SZ_OUT   = (size_t)BATCH * NRES * L0;            // floats
    constexpr size_t GATE_EL  = (size_t)NL * BATCH * NRES * FL_PAD;   // bf16 elems
    constexpr size_t H_EL     = (size_t)BATCH * NSKIP * FL_PAD;       // bf16 elems

    float* bufA = (float*)d_ws;
    float* bufB = bufA + SZ_OUT;
    __hip_bfloat16* gates = (__hip_bfloat16*)(bufB + SZ_OUT);
    __hip_bfloat16* hbuf  = gates + GATE_EL;
    __hip_bfloat16* h2buf = hbuf + H_EL;
    float* bsum = (float*)(h2buf + H_EL);

    size_t need = (size_t)(bsum + NSKIP - (float*)d_ws) * 4;
    if (ws_size < need)
        fprintf(stderr, "WS TOO SMALL: have %zu need %zu\n", ws_size, need);

    k_bias_sum<<<1, 512, 0, stream>>>(b_skip, bsum);
    k_conv_in<<<dim3(L0 / 256, BATCH), 256, 0, stream>>>(x, w_in, b_in, bufA);

    float* src = bufA;
    float* dst = bufB;
    int len = L0;
    for (int i = 0; i < NL; ++i) {
        int d = 1 << (i % 10);
        int out_len = len - d;
        dim3 grid((out_len + 255) / 256, BATCH);
        k_layer<<<grid, 256, 0, stream>>>(
            src, dst, gates + (size_t)i * BATCH * NRES * FL_PAD,
            w_sig + (size_t)i * 2048, b_sig + i * 32,
            w_tanh + (size_t)i * 2048, b_tanh + i * 32,
            w_res + (size_t)i * 1024, b_res + i * 32,
            d, out_len);
        float* tmp = src; src = dst; dst = tmp;
        len = out_len;
    }

    const int LT = (FINAL_LEN + 127) / 128;  // 89
    k_gemm<1600, 0, true,  true ><<<dim3(LT, 4, BATCH), 256, 0, stream>>>(
        w_skip, bsum, gates, nullptr, hbuf, NSKIP);
    k_gemm<512,  1, true,  true ><<<dim3(LT, 4, BATCH), 256, 0, stream>>>(
        w_p1, b_p1, hbuf, nullptr, h2buf, NSKIP);
    k_gemm<512,  1, false, false><<<dim3(LT, 2, BATCH), 256, 0, stream>>>(
        w_p2, b_p2, h2buf, out, nullptr, 256);
}

// Round 2
// 4080.479 us; speedup vs baseline: 1.6056x; 1.6056x over previous
//
#include <hip/hip_runtime.h>
#include <hip/hip_bf16.h>
#include <cstdio>
#include <cstdint>

#define BATCH 8
#define CIN 256
#define L0 16384
#define NRES 32
#define NSKIP 512
#define NL 50
#define FINAL_LEN 11269
#define NTROW 11392  // 89 * 128 column-tile rows

typedef __attribute__((ext_vector_type(4))) float f32x4v;
typedef __attribute__((ext_vector_type(8))) short s16x8;
typedef __attribute__((ext_vector_type(4))) short s16x4;

// 16B-chunk swizzle within 64B rows: involution, gives 2-way-max bank aliasing
__device__ __forceinline__ int SWS(int r, int s) {
    return s ^ (r & 3) ^ ((r >> 2) & 1);
}
__device__ __forceinline__ short f2bf(float f) {
    __hip_bfloat16 h = __float2bfloat16(f);
    return *reinterpret_cast<short*>(&h);
}
__device__ __forceinline__ float bfr(unsigned short u) {
    union { unsigned int i; float f; } v; v.i = ((unsigned int)u) << 16; return v.f;
}
__device__ __forceinline__ void gload16(const void* g, void* l) {
    __builtin_amdgcn_global_load_lds(
        (const __attribute__((address_space(1))) unsigned int*)g,
        (__attribute__((address_space(3))) unsigned int*)l, 16, 0, 0);
}

// ---------------------------------------------------------------- bias sum
__global__ void k_bias_sum(const float* __restrict__ b_skip, float* __restrict__ bsum) {
    int o = threadIdx.x;
    if (o < NSKIP) {
        float s = 0.f;
        for (int i = 0; i < NL; ++i) s += b_skip[i * NSKIP + o];
        bsum[o] = s;
    }
}

// ---------------------------------------------------------------- weight converts (fp32 -> bf16, pre-swizzled)
// w_skip [50][512][32] -> Askip [512][1600]
__global__ __launch_bounds__(256) void k_cvt_skip(const float* __restrict__ w, short* __restrict__ out) {
    int idx = blockIdx.x * 256 + threadIdx.x;
    if (idx >= NSKIP * NL) return;
    int o = idx % NSKIP, ly = idx / NSKIP;
    const float* src = w + ((size_t)ly * NSKIP + o) * NRES;
    size_t base = (size_t)o * (NL * NRES) + ly * NRES;
#pragma unroll
    for (int s = 0; s < 4; ++s) {
        s16x8 v;
#pragma unroll
        for (int j = 0; j < 8; ++j) v[j] = f2bf(src[s * 8 + j]);
        *reinterpret_cast<s16x8*>(out + base + SWS(o & 7, s) * 8) = v;
    }
}

// W[M][512] -> out[M][512]
__global__ __launch_bounds__(256) void k_cvt_mat(const float* __restrict__ w, short* __restrict__ out, int M) {
    int idx = blockIdx.x * 256 + threadIdx.x;
    if (idx >= M * 16) return;
    int m = idx >> 4, kc = idx & 15;
    const float* src = w + (size_t)m * 512 + kc * 32;
    size_t base = (size_t)m * 512 + kc * 32;
#pragma unroll
    for (int s = 0; s < 4; ++s) {
        s16x8 v;
#pragma unroll
        for (int j = 0; j < 8; ++j) v[j] = f2bf(src[s * 8 + j]);
        *reinterpret_cast<s16x8*>(out + base + SWS(m & 7, s) * 8) = v;
    }
}

// ---------------------------------------------------------------- zero gatesT tail rows
__global__ __launch_bounds__(256) void k_zero_tail(short* __restrict__ gT) {
    int i = blockIdx.x * 256 + threadIdx.x;
    const int per_b = (NTROW - FINAL_LEN) * 200;
    if (i >= BATCH * per_b) return;
    int b = i / per_b, r = i % per_b;
    int row = FINAL_LEN + r / 200, c = r % 200;
    s16x8 z = {0, 0, 0, 0, 0, 0, 0, 0};
    *reinterpret_cast<s16x8*>(gT + ((size_t)b * NTROW + row) * (NL * NRES) + c * 8) = z;
}

// ---------------------------------------------------------------- input 1x1 conv 256->32
__global__ __launch_bounds__(256) void k_conv_in(
    const float* __restrict__ x, const float* __restrict__ w,
    const float* __restrict__ bias, float* __restrict__ out) {
    const int b = blockIdx.y;
    const int t = blockIdx.x * 256 + threadIdx.x;
    float acc[NRES];
#pragma unroll
    for (int o = 0; o < NRES; ++o) acc[o] = bias[o];
    const float* xp = x + (size_t)b * CIN * L0 + t;
    for (int c = 0; c < CIN; ++c) {
        float xv = xp[(size_t)c * L0];
#pragma unroll
        for (int o = 0; o < NRES; ++o) acc[o] = fmaf(w[o * CIN + c], xv, acc[o]);
    }
    float* op = out + (size_t)b * NRES * L0 + t;
#pragma unroll
    for (int o = 0; o < NRES; ++o) op[(size_t)o * L0] = acc[o];
}

// ---------------------------------------------------------------- one WaveNet layer
__global__ __launch_bounds__(256) void k_layer(
    const float* __restrict__ src, float* __restrict__ dst,
    short* __restrict__ gout,   // gatesT + layer*32, layout [b][NTROW][1600] bf16, swizzled
    const float* __restrict__ wsig, const float* __restrict__ bsig,
    const float* __restrict__ wtan, const float* __restrict__ btan,
    const float* __restrict__ wres, const float* __restrict__ bres,
    int d, int out_len) {
    const int b = blockIdx.y;
    const int t = blockIdx.x * 256 + threadIdx.x;
    if (t >= out_len) return;
    const float* sp = src + (size_t)b * NRES * L0;

    float ps[NRES], pt[NRES];
#pragma unroll
    for (int o = 0; o < NRES; ++o) { ps[o] = bsig[o]; pt[o] = btan[o]; }

    for (int c = 0; c < NRES; ++c) {
        float xa = sp[(size_t)c * L0 + t];
        float xb = sp[(size_t)c * L0 + t + d];
#pragma unroll
        for (int o = 0; o < NRES; ++o) {
            ps[o] = fmaf(wsig[o * 64 + c * 2], xa, ps[o]);
            ps[o] = fmaf(wsig[o * 64 + c * 2 + 1], xb, ps[o]);
            pt[o] = fmaf(wtan[o * 64 + c * 2], xa, pt[o]);
            pt[o] = fmaf(wtan[o * 64 + c * 2 + 1], xb, pt[o]);
        }
    }

    float g[NRES];
#pragma unroll
    for (int o = 0; o < NRES; ++o) {
        float s  = 1.f / (1.f + __expf(-ps[o]));
        float e2 = __expf(2.f * pt[o]);
        float th = 1.f - 2.f / (e2 + 1.f);
        g[o] = s * th;
    }

    float* dp = dst + (size_t)b * NRES * L0;
#pragma unroll
    for (int o = 0; o < NRES; ++o) {
        float r = bres[o];
#pragma unroll
        for (int c = 0; c < NRES; ++c) r = fmaf(wres[o * 32 + c], g[c], r);
        dp[(size_t)o * L0 + t] = r + sp[(size_t)o * L0 + t + d];
    }

    const int t0 = out_len - FINAL_LEN;
    if (t >= t0) {
        const int tg = t - t0;
        size_t rowbase = ((size_t)b * NTROW + tg) * (NL * NRES);
#pragma unroll
        for (int s = 0; s < 4; ++s) {
            s16x8 v;
#pragma unroll
            for (int j = 0; j < 8; ++j) v[j] = f2bf(g[s * 8 + j]);
            *reinterpret_cast<s16x8*>(gout + rowbase + SWS(tg & 7, s) * 8) = v;
        }
    }
}

// ---------------------------------------------------------------- MFMA GEMM
// C[M][NTROW] = A[M][KTOT] * B^T rows [bb][NTROW][KTOT], all bf16 pre-swizzled.
// OUTMODE 0: staged bf16 out [bb][NTROW][512] (swizzled); OUTMODE 1: fp32 out[bb][Mtot][FINAL_LEN]
template <int KTOT, bool DOELU, int OUTMODE>
__global__ __launch_bounds__(256) void k_mm(
    const short* __restrict__ A, const float* __restrict__ bias,
    const short* __restrict__ B, short* __restrict__ outS,
    float* __restrict__ outF, int Mtot) {
    const int tid = threadIdx.x;
    const int l = tid & 63, w = tid >> 6;
    const int t0 = blockIdx.x * 128;
    const int m0 = blockIdx.y * 128;
    const int bb = blockIdx.z;

    __shared__ __attribute__((aligned(16))) char Asm_[2][8192];
    __shared__ __attribute__((aligned(16))) char Bsm_[2][8192];

    const char* Ag = (const char*)A;
    const char* Bg = (const char*)B + (size_t)bb * NTROW * (KTOT * 2);

    const int rstage = w * 16 + (l >> 2);
    const char* a0 = Ag + (size_t)(m0 + rstage) * (KTOT * 2) + (l & 3) * 16;
    const char* a1 = a0 + (size_t)64 * (KTOT * 2);
    const char* b0 = Bg + (size_t)(t0 + rstage) * (KTOT * 2) + (l & 3) * 16;
    const char* b1 = b0 + (size_t)64 * (KTOT * 2);

    const int wm = (w >> 1) * 64, wn = (w & 1) * 64;
    const int slotSw = ((l >> 4) ^ (l & 3) ^ ((l >> 2) & 1)) * 16;
    const int aoff = (wm + (l & 15)) * 64 + slotSw;
    const int boff = (wn + (l & 15)) * 64 + slotSw;

    f32x4v acc[4][4];
#pragma unroll
    for (int i = 0; i < 4; ++i)
#pragma unroll
        for (int j = 0; j < 4; ++j) acc[i][j] = {0.f, 0.f, 0.f, 0.f};

    constexpr int NKT = KTOT / 32;
    gload16(a0, &Asm_[0][w * 1024]);
    gload16(a1, &Asm_[0][4096 + w * 1024]);
    gload16(b0, &Bsm_[0][w * 1024]);
    gload16(b1, &Bsm_[0][4096 + w * 1024]);
    __syncthreads();

    for (int kt = 0; kt < NKT; ++kt) {
        const int cur = kt & 1;
        if (kt + 1 < NKT) {
            size_t ko = (size_t)(kt + 1) * 64;
            gload16(a0 + ko, &Asm_[cur ^ 1][w * 1024]);
            gload16(a1 + ko, &Asm_[cur ^ 1][4096 + w * 1024]);
            gload16(b0 + ko, &Bsm_[cur ^ 1][w * 1024]);
            gload16(b1 + ko, &Bsm_[cur ^ 1][4096 + w * 1024]);
        }
        s16x8 af[4], bf_[4];
#pragma unroll
        for (int i = 0; i < 4; ++i)
            af[i] = *reinterpret_cast<const s16x8*>(&Asm_[cur][aoff + i * 1024]);
#pragma unroll
        for (int i = 0; i < 4; ++i)
            bf_[i] = *reinterpret_cast<const s16x8*>(&Bsm_[cur][boff + i * 1024]);
#pragma unroll
        for (int i = 0; i < 4; ++i)
#pragma unroll
            for (int j = 0; j < 4; ++j)
                acc[i][j] = __builtin_amdgcn_mfma_f32_16x16x32_bf16(af[i], bf_[j], acc[i][j], 0, 0, 0);
        __syncthreads();
    }

    // epilogue: D[(l/16)*4+j][l%16]
    const int colc = l & 15;
    const int rowc = (l >> 4) * 4;
#pragma unroll
    for (int mf = 0; mf < 4; ++mf) {
        const int ch = m0 + wm + mf * 16 + rowc;
        const float4 bv = *reinterpret_cast<const float4*>(&bias[ch]);
        const float* bvp = (const float*)&bv;
#pragma unroll
        for (int nf = 0; nf < 4; ++nf) {
            const int t = t0 + wn + nf * 16 + colc;
            float vb[4];
#pragma unroll
            for (int j = 0; j < 4; ++j) {
                float v = acc[mf][nf][j] + bvp[j];
                if (DOELU) v = v > 0.f ? v : (__expf(v) - 1.f);
                vb[j] = v;
            }
            if (OUTMODE == 0) {
                s16x4 pv;
#pragma unroll
                for (int j = 0; j < 4; ++j) pv[j] = f2bf(vb[j]);
                size_t el = ((size_t)bb * NTROW + t) * 512 + (ch >> 5) * 32
                          + SWS(t & 7, (ch >> 3) & 3) * 8 + (ch & 7);
                *reinterpret_cast<s16x4*>(outS + el) = pv;
            } else {
                if (t < FINAL_LEN) {
#pragma unroll
                    for (int j = 0; j < 4; ++j)
                        outF[((size_t)bb * Mtot + ch + j) * FINAL_LEN + t] = vb[j];
                }
            }
        }
    }
}

// ---------------------------------------------------------------- host
extern "C" void kernel_launch(void* const* d_in, const int* in_sizes, int n_in,
                              void* d_out, int out_size, void* d_ws, size_t ws_size,
                              hipStream_t stream) {
    const float* x      = (const float*)d_in[0];
    const float* w_in   = (const float*)d_in[1];
    const float* b_in   = (const float*)d_in[2];
    const float* w_sig  = (const float*)d_in[3];
    const float* b_sig  = (const float*)d_in[4];
    const float* w_tanh = (const float*)d_in[5];
    const float* b_tanh = (const float*)d_in[6];
    const float* w_skip = (const float*)d_in[7];
    const float* b_skip = (const float*)d_in[8];
    const float* w_res  = (const float*)d_in[9];
    const float* b_res  = (const float*)d_in[10];
    const float* w_p1   = (const float*)d_in[11];
    const float* b_p1   = (const float*)d_in[12];
    const float* w_p2   = (const float*)d_in[13];
    const float* b_p2   = (const float*)d_in[14];
    float* out = (float*)d_out;

    float* bufA  = (float*)d_ws;
    float* bufB  = bufA + (size_t)BATCH * NRES * L0;
    float* bsum  = bufB + (size_t)BATCH * NRES * L0;
    short* Askip = (short*)(bsum + NSKIP);
    short* Ap1   = Askip + (size_t)NSKIP * NL * NRES;
    short* Ap2   = Ap1 + (size_t)NSKIP * NSKIP;
    short* gatesT = Ap2 + (size_t)CIN * NSKIP;
    short* hbufT  = gatesT + (size_t)BATCH * NTROW * (NL * NRES);
    short* h2bufT = gatesT;  // alias: gatesT dead after skip GEMM

    size_t need = (size_t)((char*)(hbufT + (size_t)BATCH * NTROW * NSKIP) - (char*)d_ws);
    if (ws_size < need)
        fprintf(stderr, "WS TOO SMALL: have %zu need %zu\n", ws_size, need);

    k_bias_sum<<<1, 512, 0, stream>>>(b_skip, bsum);
    k_cvt_skip<<<(NSKIP * NL + 255) / 256, 256, 0, stream>>>(w_skip, Askip);
    k_cvt_mat<<<(NSKIP * 16 + 255) / 256, 256, 0, stream>>>(w_p1, Ap1, NSKIP);
    k_cvt_mat<<<(CIN * 16 + 255) / 256, 256, 0, stream>>>(w_p2, Ap2, CIN);
    k_zero_tail<<<(BATCH * (NTROW - FINAL_LEN) * 200 + 255) / 256, 256, 0, stream>>>(gatesT);
    k_conv_in<<<dim3(L0 / 256, BATCH), 256, 0, stream>>>(x, w_in, b_in, bufA);

    float* src = bufA;
    float* dst = bufB;
    int len = L0;
    for (int i = 0; i < NL; ++i) {
        int d = 1 << (i % 10);
        int out_len = len - d;
        dim3 grid((out_len + 255) / 256, BATCH);
        k_layer<<<grid, 256, 0, stream>>>(
            src, dst, gatesT + (size_t)i * NRES,
            w_sig + (size_t)i * 2048, b_sig + i * 32,
            w_tanh + (size_t)i * 2048, b_tanh + i * 32,
            w_res + (size_t)i * 1024, b_res + i * 32,
            d, out_len);
        float* tmp = src; src = dst; dst = tmp;
        len = out_len;
    }

    k_mm<1600, true, 0><<<dim3(89, 4, BATCH), 256, 0, stream>>>(Askip, bsum, gatesT, hbufT, nullptr, NSKIP);
    k_mm<512,  true, 0><<<dim3(89, 4, BATCH), 256, 0, stream>>>(Ap1, b_p1, hbufT, h2bufT, nullptr, NSKIP);
    k_mm<512, false, 1><<<dim3(89, 2, BATCH), 256, 0, stream>>>(Ap2, b_p2, h2bufT, nullptr, out, CIN);
}

// Round 3
// 1622.809 us; speedup vs baseline: 4.0372x; 2.5145x over previous
//
#include <hip/hip_runtime.h>
#include <hip/hip_bf16.h>
#include <cstdio>
#include <cstdint>

#define BATCH 8
#define CIN 256
#define L0 16384
#define NRES 32
#define NSKIP 512
#define NL 50
#define FINAL_LEN 11269
#define NTROW 11392  // 89 * 128 column-tile rows

typedef __attribute__((ext_vector_type(4))) float f32x4v;
typedef __attribute__((ext_vector_type(8))) short s16x8;
typedef __attribute__((ext_vector_type(4))) short s16x4;

// 16B-chunk swizzle within 64B rows: involution, gives 2-way-max bank aliasing
__device__ __forceinline__ int SWS(int r, int s) {
    return s ^ (r & 3) ^ ((r >> 2) & 1);
}
__device__ __forceinline__ short f2bf(float f) {
    __hip_bfloat16 h = __float2bfloat16(f);
    return *reinterpret_cast<short*>(&h);
}
__device__ __forceinline__ void gload16(const void* g, void* l) {
    __builtin_amdgcn_global_load_lds(
        (const __attribute__((address_space(1))) unsigned int*)g,
        (__attribute__((address_space(3))) unsigned int*)l, 16, 0, 0);
}

// ---------------------------------------------------------------- bias sum
__global__ void k_bias_sum(const float* __restrict__ b_skip, float* __restrict__ bsum) {
    int o = threadIdx.x;
    if (o < NSKIP) {
        float s = 0.f;
        for (int i = 0; i < NL; ++i) s += b_skip[i * NSKIP + o];
        bsum[o] = s;
    }
}

// ---------------------------------------------------------------- weight converts (fp32 -> bf16, pre-swizzled)
__global__ __launch_bounds__(256) void k_cvt_skip(const float* __restrict__ w, short* __restrict__ out) {
    int idx = blockIdx.x * 256 + threadIdx.x;
    if (idx >= NSKIP * NL) return;
    int o = idx % NSKIP, ly = idx / NSKIP;
    const float* src = w + ((size_t)ly * NSKIP + o) * NRES;
    size_t base = (size_t)o * (NL * NRES) + ly * NRES;
#pragma unroll
    for (int s = 0; s < 4; ++s) {
        s16x8 v;
#pragma unroll
        for (int j = 0; j < 8; ++j) v[j] = f2bf(src[s * 8 + j]);
        *reinterpret_cast<s16x8*>(out + base + SWS(o & 7, s) * 8) = v;
    }
}

__global__ __launch_bounds__(256) void k_cvt_mat(const float* __restrict__ w, short* __restrict__ out, int M) {
    int idx = blockIdx.x * 256 + threadIdx.x;
    if (idx >= M * 16) return;
    int m = idx >> 4, kc = idx & 15;
    const float* src = w + (size_t)m * 512 + kc * 32;
    size_t base = (size_t)m * 512 + kc * 32;
#pragma unroll
    for (int s = 0; s < 4; ++s) {
        s16x8 v;
#pragma unroll
        for (int j = 0; j < 8; ++j) v[j] = f2bf(src[s * 8 + j]);
        *reinterpret_cast<s16x8*>(out + base + SWS(m & 7, s) * 8) = v;
    }
}

// combined gated-conv weights: Wc[i][64 out][64 k], k = tap*32 + c ; Wres[i][32][32]
__global__ __launch_bounds__(256) void k_cvt_w(
    const float* __restrict__ ws, const float* __restrict__ wt, const float* __restrict__ wr,
    short* __restrict__ Wc, short* __restrict__ Wres) {
    int idx = blockIdx.x * 256 + threadIdx.x;
    if (idx < NL * 64 * 64) {
        int k = idx & 63, o = (idx >> 6) & 63, i = idx >> 12;
        int c = k & 31, tap = k >> 5;
        float v = (o < 32) ? ws[((i * NRES + o) * NRES + c) * 2 + tap]
                           : wt[((i * NRES + (o - 32)) * NRES + c) * 2 + tap];
        Wc[idx] = f2bf(v);
    } else {
        int j = idx - NL * 64 * 64;
        if (j < NL * 32 * 32) Wres[j] = f2bf(wr[j]);
    }
}

// ---------------------------------------------------------------- zero gatesT tail rows
__global__ __launch_bounds__(256) void k_zero_tail(short* __restrict__ gT) {
    int i = blockIdx.x * 256 + threadIdx.x;
    const int per_b = (NTROW - FINAL_LEN) * 200;
    if (i >= BATCH * per_b) return;
    int b = i / per_b, r = i % per_b;
    int row = FINAL_LEN + r / 200, c = r % 200;
    s16x8 z = {0, 0, 0, 0, 0, 0, 0, 0};
    *reinterpret_cast<s16x8*>(gT + ((size_t)b * NTROW + row) * (NL * NRES) + c * 8) = z;
}

// ---------------------------------------------------------------- input 1x1 conv 256->32 (+ bf16 shadow)
__global__ __launch_bounds__(256) void k_conv_in(
    const float* __restrict__ x, const float* __restrict__ w,
    const float* __restrict__ bias, float* __restrict__ out, short* __restrict__ outH) {
    const int b = blockIdx.y;
    const int t = blockIdx.x * 256 + threadIdx.x;
    float acc[NRES];
#pragma unroll
    for (int o = 0; o < NRES; ++o) acc[o] = bias[o];
    const float* xp = x + (size_t)b * CIN * L0 + t;
    for (int c = 0; c < CIN; ++c) {
        float xv = xp[(size_t)c * L0];
#pragma unroll
        for (int o = 0; o < NRES; ++o) acc[o] = fmaf(w[o * CIN + c], xv, acc[o]);
    }
    float* op = out + (size_t)b * NRES * L0 + t;
#pragma unroll
    for (int o = 0; o < NRES; ++o) op[(size_t)o * L0] = acc[o];
    short* hp = outH + ((size_t)b * L0 + t) * NRES;
#pragma unroll
    for (int s = 0; s < 4; ++s) {
        s16x8 v;
#pragma unroll
        for (int j = 0; j < 8; ++j) v[j] = f2bf(acc[s * 8 + j]);
        *reinterpret_cast<s16x8*>(hp + s * 8) = v;
    }
}

// ---------------------------------------------------------------- MFMA WaveNet layer
// srcF fp32 [b][32][L0]; srcH bf16 shadow [b][L0][32]; per-wave 64 t columns.
__global__ __launch_bounds__(256) void k_layer_mfma(
    const float* __restrict__ srcF, const short* __restrict__ srcH,
    float* __restrict__ dstF, short* __restrict__ dstH,
    short* __restrict__ gout,          // gatesT + layer*32
    const short* __restrict__ Wc,      // [64][64] this layer
    const short* __restrict__ Wr,      // [32][32] this layer
    const float* __restrict__ bsig, const float* __restrict__ btan,
    const float* __restrict__ bres, int d, int out_len) {
    const int tid = threadIdx.x;
    const int l = tid & 63, w = tid >> 6;
    const int lr = l & 15, lg = l >> 4;
    const int b = blockIdx.y;
    const int t0w = blockIdx.x * 256 + w * 64;
    const int t0g = out_len - FINAL_LEN;

    __shared__ short gsm[4][64][40];  // gates, row pad 40 shorts (16B-aligned rows, 2-way banks max)
    __shared__ short hsm[4][64][40];  // residual-out bf16 for coalesced repack

    // op0 fragments (verified convention: M[l&15][(l>>4)*8+i])
    s16x8 aW[4][2];
#pragma unroll
    for (int mf = 0; mf < 4; ++mf)
#pragma unroll
        for (int kf = 0; kf < 2; ++kf)
            aW[mf][kf] = *reinterpret_cast<const s16x8*>(&Wc[(mf * 16 + lr) * 64 + kf * 32 + lg * 8]);
    s16x8 aR[2];
#pragma unroll
    for (int mf = 0; mf < 2; ++mf)
        aR[mf] = *reinterpret_cast<const s16x8*>(&Wr[(mf * 16 + lr) * 32 + lg * 8]);

    float bs[2][4], bt[2][4], br[2][4];
#pragma unroll
    for (int mf = 0; mf < 2; ++mf)
#pragma unroll
        for (int j = 0; j < 4; ++j) {
            int o = mf * 16 + lg * 4 + j;
            bs[mf][j] = bsig[o]; bt[mf][j] = btan[o]; br[mf][j] = bres[o];
        }

    const float* sF = srcF + (size_t)b * NRES * L0;
    const short* sH = srcH + (size_t)b * L0 * NRES;
    float* dF = dstF + (size_t)b * NRES * L0;

#pragma unroll 1
    for (int nf = 0; nf < 4; ++nf) {
        const int tl = nf * 16 + lr;
        const int t = t0w + tl;
        const int tc = t < out_len ? t : (out_len - 1);
        // op1 fragments direct from global (t-major shadow: one 16B load each)
        s16x8 bx0 = *reinterpret_cast<const s16x8*>(&sH[(size_t)tc * NRES + lg * 8]);
        s16x8 bx1 = *reinterpret_cast<const s16x8*>(&sH[(size_t)(tc + d) * NRES + lg * 8]);

        f32x4v acc[4];
#pragma unroll
        for (int mf = 0; mf < 4; ++mf) acc[mf] = {0.f, 0.f, 0.f, 0.f};
#pragma unroll
        for (int mf = 0; mf < 4; ++mf) {
            acc[mf] = __builtin_amdgcn_mfma_f32_16x16x32_bf16(aW[mf][0], bx0, acc[mf], 0, 0, 0);
            acc[mf] = __builtin_amdgcn_mfma_f32_16x16x32_bf16(aW[mf][1], bx1, acc[mf], 0, 0, 0);
        }

        // gate nonlinearity: sig frag mf, tanh frag mf+2 — same lane, same slot
#pragma unroll
        for (int mf = 0; mf < 2; ++mf) {
            s16x4 gq;
#pragma unroll
            for (int j = 0; j < 4; ++j) {
                float Ps = acc[mf][j] + bs[mf][j];
                float Pt = acc[mf + 2][j] + bt[mf][j];
                float sg = 1.f / (1.f + __expf(-Ps));
                float e2 = __expf(2.f * Pt);
                float th = 1.f - 2.f / (e2 + 1.f);
                gq[j] = f2bf(sg * th);
            }
            *reinterpret_cast<s16x4*>(&gsm[w][tl][mf * 16 + lg * 4]) = gq;
        }
        __syncthreads();

        // res matmul: op1 from gsm
        s16x8 bg = *reinterpret_cast<const s16x8*>(&gsm[w][tl][lg * 8]);
        f32x4v accR[2];
#pragma unroll
        for (int mf = 0; mf < 2; ++mf) {
            accR[mf] = {0.f, 0.f, 0.f, 0.f};
            accR[mf] = __builtin_amdgcn_mfma_f32_16x16x32_bf16(aR[mf], bg, accR[mf], 0, 0, 0);
        }

        if (t < out_len) {
#pragma unroll
            for (int mf = 0; mf < 2; ++mf) {
                s16x4 hq;
#pragma unroll
                for (int j = 0; j < 4; ++j) {
                    int o = mf * 16 + lg * 4 + j;
                    float v = accR[mf][j] + br[mf][j] + sF[(size_t)o * L0 + t + d];
                    dF[(size_t)o * L0 + t] = v;
                    hq[j] = f2bf(v);
                }
                *reinterpret_cast<s16x4*>(&hsm[w][tl][mf * 16 + lg * 4]) = hq;
            }
        }
    }
    __syncthreads();

    // coalesced repack: shadow + gates (full 64B-line stores; SWS permutes chunks within 64B)
    short* dH = dstH + (size_t)b * L0 * NRES;
#pragma unroll
    for (int k = 0; k < 4; ++k) {
        int r = k * 16 + (l >> 2);
        int t = t0w + r;
        int c = l & 3;
        if (t < out_len) {
            s16x8 hv = *reinterpret_cast<const s16x8*>(&hsm[w][r][c * 8]);
            *reinterpret_cast<s16x8*>(&dH[(size_t)t * NRES + c * 8]) = hv;
            if (t >= t0g) {
                int tg = t - t0g;
                s16x8 gv = *reinterpret_cast<const s16x8*>(&gsm[w][r][c * 8]);
                *reinterpret_cast<s16x8*>(
                    &gout[((size_t)b * NTROW + tg) * (NL * NRES) + SWS(tg & 7, c) * 8]) = gv;
            }
        }
    }
}

// ---------------------------------------------------------------- MFMA GEMM (unchanged from round 2)
template <int KTOT, bool DOELU, int OUTMODE>
__global__ __launch_bounds__(256) void k_mm(
    const short* __restrict__ A, const float* __restrict__ bias,
    const short* __restrict__ B, short* __restrict__ outS,
    float* __restrict__ outF, int Mtot) {
    const int tid = threadIdx.x;
    const int l = tid & 63, w = tid >> 6;
    const int t0 = blockIdx.x * 128;
    const int m0 = blockIdx.y * 128;
    const int bb = blockIdx.z;

    __shared__ __attribute__((aligned(16))) char Asm_[2][8192];
    __shared__ __attribute__((aligned(16))) char Bsm_[2][8192];

    const char* Ag = (const char*)A;
    const char* Bg = (const char*)B + (size_t)bb * NTROW * (KTOT * 2);

    const int rstage = w * 16 + (l >> 2);
    const char* a0 = Ag + (size_t)(m0 + rstage) * (KTOT * 2) + (l & 3) * 16;
    const char* a1 = a0 + (size_t)64 * (KTOT * 2);
    const char* b0 = Bg + (size_t)(t0 + rstage) * (KTOT * 2) + (l & 3) * 16;
    const char* b1 = b0 + (size_t)64 * (KTOT * 2);

    const int wm = (w >> 1) * 64, wn = (w & 1) * 64;
    const int slotSw = ((l >> 4) ^ (l & 3) ^ ((l >> 2) & 1)) * 16;
    const int aoff = (wm + (l & 15)) * 64 + slotSw;
    const int boff = (wn + (l & 15)) * 64 + slotSw;

    f32x4v acc[4][4];
#pragma unroll
    for (int i = 0; i < 4; ++i)
#pragma unroll
        for (int j = 0; j < 4; ++j) acc[i][j] = {0.f, 0.f, 0.f, 0.f};

    constexpr int NKT = KTOT / 32;
    gload16(a0, &Asm_[0][w * 1024]);
    gload16(a1, &Asm_[0][4096 + w * 1024]);
    gload16(b0, &Bsm_[0][w * 1024]);
    gload16(b1, &Bsm_[0][4096 + w * 1024]);
    __syncthreads();

    for (int kt = 0; kt < NKT; ++kt) {
        const int cur = kt & 1;
        if (kt + 1 < NKT) {
            size_t ko = (size_t)(kt + 1) * 64;
            gload16(a0 + ko, &Asm_[cur ^ 1][w * 1024]);
            gload16(a1 + ko, &Asm_[cur ^ 1][4096 + w * 1024]);
            gload16(b0 + ko, &Bsm_[cur ^ 1][w * 1024]);
            gload16(b1 + ko, &Bsm_[cur ^ 1][4096 + w * 1024]);
        }
        s16x8 af[4], bf_[4];
#pragma unroll
        for (int i = 0; i < 4; ++i)
            af[i] = *reinterpret_cast<const s16x8*>(&Asm_[cur][aoff + i * 1024]);
#pragma unroll
        for (int i = 0; i < 4; ++i)
            bf_[i] = *reinterpret_cast<const s16x8*>(&Bsm_[cur][boff + i * 1024]);
#pragma unroll
        for (int i = 0; i < 4; ++i)
#pragma unroll
            for (int j = 0; j < 4; ++j)
                acc[i][j] = __builtin_amdgcn_mfma_f32_16x16x32_bf16(af[i], bf_[j], acc[i][j], 0, 0, 0);
        __syncthreads();
    }

    const int colc = l & 15;
    const int rowc = (l >> 4) * 4;
#pragma unroll
    for (int mf = 0; mf < 4; ++mf) {
        const int ch = m0 + wm + mf * 16 + rowc;
        const float4 bv = *reinterpret_cast<const float4*>(&bias[ch]);
        const float* bvp = (const float*)&bv;
#pragma unroll
        for (int nf = 0; nf < 4; ++nf) {
            const int t = t0 + wn + nf * 16 + colc;
            float vb[4];
#pragma unroll
            for (int j = 0; j < 4; ++j) {
                float v = acc[mf][nf][j] + bvp[j];
                if (DOELU) v = v > 0.f ? v : (__expf(v) - 1.f);
                vb[j] = v;
            }
            if (OUTMODE == 0) {
                s16x4 pv;
#pragma unroll
                for (int j = 0; j < 4; ++j) pv[j] = f2bf(vb[j]);
                size_t el = ((size_t)bb * NTROW + t) * 512 + (ch >> 5) * 32
                          + SWS(t & 7, (ch >> 3) & 3) * 8 + (ch & 7);
                *reinterpret_cast<s16x4*>(outS + el) = pv;
            } else {
                if (t < FINAL_LEN) {
#pragma unroll
                    for (int j = 0; j < 4; ++j)
                        outF[((size_t)bb * Mtot + ch + j) * FINAL_LEN + t] = vb[j];
                }
            }
        }
    }
}

// ---------------------------------------------------------------- host
extern "C" void kernel_launch(void* const* d_in, const int* in_sizes, int n_in,
                              void* d_out, int out_size, void* d_ws, size_t ws_size,
                              hipStream_t stream) {
    const float* x      = (const float*)d_in[0];
    const float* w_in   = (const float*)d_in[1];
    const float* b_in   = (const float*)d_in[2];
    const float* w_sig  = (const float*)d_in[3];
    const float* b_sig  = (const float*)d_in[4];
    const float* w_tanh = (const float*)d_in[5];
    const float* b_tanh = (const float*)d_in[6];
    const float* w_skip = (const float*)d_in[7];
    const float* b_skip = (const float*)d_in[8];
    const float* w_res  = (const float*)d_in[9];
    const float* b_res  = (const float*)d_in[10];
    const float* w_p1   = (const float*)d_in[11];
    const float* b_p1   = (const float*)d_in[12];
    const float* w_p2   = (const float*)d_in[13];
    const float* b_p2   = (const float*)d_in[14];
    float* out = (float*)d_out;

    float* bufA   = (float*)d_ws;
    float* bufB   = bufA + (size_t)BATCH * NRES * L0;
    float* bsum   = bufB + (size_t)BATCH * NRES * L0;
    short* Askip  = (short*)(bsum + NSKIP);
    short* Ap1    = Askip + (size_t)NSKIP * NL * NRES;
    short* Ap2    = Ap1 + (size_t)NSKIP * NSKIP;
    short* WcH    = Ap2 + (size_t)CIN * NSKIP;
    short* WresH  = WcH + (size_t)NL * 64 * 64;
    short* gatesT = WresH + (size_t)NL * 32 * 32;
    short* hbufT  = gatesT + (size_t)BATCH * NTROW * (NL * NRES);
    short* h2bufT = gatesT;              // alias: gatesT dead after skip GEMM
    short* shadowA = hbufT;              // alias: shadows dead before skip GEMM writes hbufT
    short* shadowB = shadowA + (size_t)BATCH * L0 * NRES;

    size_t need = (size_t)((char*)(hbufT + (size_t)BATCH * NTROW * NSKIP) - (char*)d_ws);
    if (ws_size < need)
        fprintf(stderr, "WS TOO SMALL: have %zu need %zu\n", ws_size, need);

    k_bias_sum<<<1, 512, 0, stream>>>(b_skip, bsum);
    k_cvt_skip<<<(NSKIP * NL + 255) / 256, 256, 0, stream>>>(w_skip, Askip);
    k_cvt_mat<<<(NSKIP * 16 + 255) / 256, 256, 0, stream>>>(w_p1, Ap1, NSKIP);
    k_cvt_mat<<<(CIN * 16 + 255) / 256, 256, 0, stream>>>(w_p2, Ap2, CIN);
    k_cvt_w<<<(NL * 64 * 64 + NL * 32 * 32 + 255) / 256, 256, 0, stream>>>(
        w_sig, w_tanh, w_res, WcH, WresH);
    k_zero_tail<<<(BATCH * (NTROW - FINAL_LEN) * 200 + 255) / 256, 256, 0, stream>>>(gatesT);
    k_conv_in<<<dim3(L0 / 256, BATCH), 256, 0, stream>>>(x, w_in, b_in, bufA, shadowA);

    float* srcF = bufA;  float* dstF = bufB;
    short* srcH = shadowA; short* dstH = shadowB;
    int len = L0;
    for (int i = 0; i < NL; ++i) {
        int d = 1 << (i % 10);
        int out_len = len - d;
        dim3 grid((out_len + 255) / 256, BATCH);
        k_layer_mfma<<<grid, 256, 0, stream>>>(
            srcF, srcH, dstF, dstH, gatesT + (size_t)i * NRES,
            WcH + (size_t)i * 4096, WresH + (size_t)i * 1024,
            b_sig + i * 32, b_tanh + i * 32, b_res + i * 32, d, out_len);
        float* tf = srcF; srcF = dstF; dstF = tf;
        short* th = srcH; srcH = dstH; dstH = th;
        len = out_len;
    }

    k_mm<1600, true, 0><<<dim3(89, 4, BATCH), 256, 0, stream>>>(Askip, bsum, gatesT, hbufT, nullptr, NSKIP);
    k_mm<512,  true, 0><<<dim3(89, 4, BATCH), 256, 0, stream>>>(Ap1, b_p1, hbufT, h2bufT, nullptr, NSKIP);
    k_mm<512, false, 1><<<dim3(89, 2, BATCH), 256, 0, stream>>>(Ap2, b_p2, h2bufT, nullptr, out, CIN);
}